// Round 1
// baseline (278.964 us; speedup 1.0000x reference)
//
#include <hip/hip_runtime.h>
#include <hip/hip_bf16.h>

#define NN 6144
#define HEADS 4
#define DIN 256
#define DOUT 64

typedef __bf16 bf16_t;
typedef bf16_t bf16x8 __attribute__((ext_vector_type(8)));
typedef float f32x16 __attribute__((ext_vector_type(16)));

static __device__ __forceinline__ f32x16 zero16() {
  f32x16 z;
#pragma unroll
  for (int i = 0; i < 16; ++i) z[i] = 0.0f;
  return z;
}

static __device__ __forceinline__ bf16x8 ldg8(const bf16_t* p) {
  return *reinterpret_cast<const bf16x8*>(p);
}

// ---------------- prep: h -> bf16, W -> transposed bf16 (scale folded into WQ)
__global__ __launch_bounds__(256) void prep_kernel(
    const float* __restrict__ h, const float* __restrict__ WQ,
    const float* __restrict__ WK, const float* __restrict__ WV,
    bf16_t* __restrict__ hb, bf16_t* __restrict__ Wt) {
  int stride = gridDim.x * blockDim.x;
  int idx = blockIdx.x * blockDim.x + threadIdx.x;
  for (int i = idx; i < NN * DIN; i += stride)
    hb[i] = (bf16_t)h[i];
  const float c2 = 0.0625f * 1.4426950408889634f;  // (1/sqrt(256)) * log2(e)
  for (int i = idx; i < 3 * HEADS * DOUT * DIN; i += stride) {
    int d = i & (DIN - 1);
    int o = (i >> 8) & (DOUT - 1);
    int hh = (i >> 14) & (HEADS - 1);
    int m = i >> 16;
    const float* W = (m == 0) ? WQ : (m == 1) ? WK : WV;
    float v = W[(hh * DIN + d) * DOUT + o];
    if (m == 0) v *= c2;
    Wt[i] = (bf16_t)v;  // Wt[m][hh][o][d]
  }
}

// ---------------- proj: Qb,Kb row-major bf16 [H][N][64]; Vt bf16 [H][64][N]
__global__ __launch_bounds__(256) void proj_kernel(
    const bf16_t* __restrict__ hb, const bf16_t* __restrict__ Wt,
    const float* __restrict__ bQ, const float* __restrict__ bK,
    const float* __restrict__ bV,
    bf16_t* __restrict__ Qb, bf16_t* __restrict__ Kb, bf16_t* __restrict__ Vt) {
  const float c2 = 0.0625f * 1.4426950408889634f;
  int tid = threadIdx.x;
  int w = tid >> 6, l = tid & 63;
  int l31 = l & 31, lh = l >> 5;
  int hh = blockIdx.y;
  int n0 = blockIdx.x * 64;

#pragma unroll
  for (int s = 0; s < 3; ++s) {
    int t = w * 3 + s;  // 12 tiles: 0-3 Q, 4-7 K, 8-11 V^T
    if (t < 8) {
      int m = t >> 2;            // 0=Q, 1=K
      int rh = (t >> 1) & 1;     // row half
      int oh = t & 1;            // out-col half
      const bf16_t* arow = hb + (n0 + rh * 32 + l31) * DIN + 8 * lh;
      const bf16_t* brow = Wt + ((m * HEADS + hh) * DOUT + oh * 32 + l31) * DIN + 8 * lh;
      f32x16 acc = zero16();
#pragma unroll
      for (int kc = 0; kc < 16; ++kc)
        acc = __builtin_amdgcn_mfma_f32_32x32x16_bf16(ldg8(arow + kc * 16),
                                                      ldg8(brow + kc * 16), acc, 0, 0, 0);
      const float* bias = (m == 0) ? bQ : bK;
      float bv = bias[hh * DOUT + oh * 32 + l31];
      if (m == 0) bv *= c2;
      bf16_t* outp = ((m == 0) ? Qb : Kb) +
                     (size_t)(hh * NN + n0 + rh * 32) * DOUT + oh * 32 + l31;
#pragma unroll
      for (int r = 0; r < 16; ++r) {
        int q = (r & 3) + 8 * (r >> 2) + 4 * lh;
        outp[q * DOUT] = (bf16_t)(acc[r] + bv);
      }
    } else {
      int tt = t - 8;
      int oh = tt >> 1, nh = tt & 1;
      const bf16_t* arow = Wt + ((2 * HEADS + hh) * DOUT + oh * 32 + l31) * DIN + 8 * lh;
      const bf16_t* brow = hb + (n0 + nh * 32 + l31) * DIN + 8 * lh;
      f32x16 acc = zero16();
#pragma unroll
      for (int kc = 0; kc < 16; ++kc)
        acc = __builtin_amdgcn_mfma_f32_32x32x16_bf16(ldg8(arow + kc * 16),
                                                      ldg8(brow + kc * 16), acc, 0, 0, 0);
      bf16_t* outp = Vt + (size_t)(hh * DOUT + oh * 32) * NN + n0 + nh * 32 + l31;
#pragma unroll
      for (int r = 0; r < 16; ++r) {
        int o = (r & 3) + 8 * (r >> 2) + 4 * lh;
        float bvv = bV[hh * DOUT + oh * 32 + o];
        outp[o * NN] = (bf16_t)(acc[r] + bvv);
      }
    }
  }
}

// ---------------- attention: flash-style, no-max softmax (bounded logits)
__global__ __launch_bounds__(256, 2) void attn_kernel(
    const float* __restrict__ adj, const bf16_t* __restrict__ Qb,
    const bf16_t* __restrict__ Kb, const bf16_t* __restrict__ Vt,
    float* __restrict__ out) {
  __shared__ __align__(16) bf16_t Plds[4][32 * 72];  // per-wave P, stride 72 (pad)
  __shared__ float Opart[4][32][64];
  __shared__ float Ssum[4][32];

  int tid = threadIdx.x;
  int w = tid >> 6, l = tid & 63;
  int l31 = l & 31, lh = l >> 5;
  int hh = blockIdx.y;
  int q0 = blockIdx.x * 32;

  // Q fragments (scaled by c2 already): A-frag lane holds row l31, k = kc*16+8*lh..+7
  const bf16_t* Qrow = Qb + (size_t)(hh * NN + q0 + l31) * DOUT + 8 * lh;
  bf16x8 qf[4];
#pragma unroll
  for (int kc = 0; kc < 4; ++kc) qf[kc] = ldg8(Qrow + kc * 16);

  const bf16_t* Kbase = Kb + (size_t)hh * NN * DOUT;
  const bf16_t* Vbase = Vt + (size_t)hh * DOUT * NN;
  const float* adjbase = adj + (size_t)hh * NN * NN + (size_t)q0 * NN;

  bf16_t* myP = &Plds[w][0];

  f32x16 o0 = zero16(), o1 = zero16();
  float sacc[16];
#pragma unroll
  for (int r = 0; r < 16; ++r) sacc[r] = 0.0f;

  for (int it = 0; it < 24; ++it) {
    int key0 = (it * 4 + w) * 64;  // each wave owns disjoint 64-key chunks
    f32x16 s0 = zero16(), s1 = zero16();
    const bf16_t* krow = Kbase + (key0 + l31) * DOUT + 8 * lh;
#pragma unroll
    for (int kc = 0; kc < 4; ++kc) {
      s0 = __builtin_amdgcn_mfma_f32_32x32x16_bf16(qf[kc], ldg8(krow + kc * 16), s0, 0, 0, 0);
      s1 = __builtin_amdgcn_mfma_f32_32x32x16_bf16(qf[kc], ldg8(krow + 32 * DOUT + kc * 16), s1, 0, 0, 0);
    }
    // p = exp2(S * adj); accumulate row sums; stash P in LDS (bf16)
#pragma unroll
    for (int r = 0; r < 16; ++r) {
      int q = (r & 3) + 8 * (r >> 2) + 4 * lh;
      const float* ap = adjbase + (size_t)q * NN + key0 + l31;
      float p0 = exp2f(s0[r] * ap[0]);
      float p1 = exp2f(s1[r] * ap[32]);
      sacc[r] += p0 + p1;
      myP[q * 72 + l31] = (bf16_t)p0;
      myP[q * 72 + 32 + l31] = (bf16_t)p1;
    }
    // O += P * V   (A-frag from LDS, B-frag from V^T)
    const bf16_t* vrow = Vbase + l31 * NN + key0 + 8 * lh;
#pragma unroll
    for (int kc = 0; kc < 4; ++kc) {
      bf16x8 pa = *reinterpret_cast<const bf16x8*>(&myP[l31 * 72 + kc * 16 + 8 * lh]);
      o0 = __builtin_amdgcn_mfma_f32_32x32x16_bf16(pa, ldg8(vrow + kc * 16), o0, 0, 0, 0);
      o1 = __builtin_amdgcn_mfma_f32_32x32x16_bf16(pa, ldg8(vrow + 32 * NN + kc * 16), o1, 0, 0, 0);
    }
  }

  // reduce row-sums across the 32-lane halves (keys live along lanes)
#pragma unroll
  for (int r = 0; r < 16; ++r) {
    float v = sacc[r];
    v += __shfl_xor(v, 1);
    v += __shfl_xor(v, 2);
    v += __shfl_xor(v, 4);
    v += __shfl_xor(v, 8);
    v += __shfl_xor(v, 16);
    sacc[r] = v;
  }
  if (l31 == 0) {
#pragma unroll
    for (int r = 0; r < 16; ++r) {
      int q = (r & 3) + 8 * (r >> 2) + 4 * lh;
      Ssum[w][q] = sacc[r];
    }
  }
#pragma unroll
  for (int r = 0; r < 16; ++r) {
    int q = (r & 3) + 8 * (r >> 2) + 4 * lh;
    Opart[w][q][l31] = o0[r];
    Opart[w][q][32 + l31] = o1[r];
  }
  __syncthreads();

  // combine 4 wave-partials, normalize, write out
#pragma unroll
  for (int k = 0; k < 8; ++k) {
    int idx = tid + 256 * k;
    int q = idx >> 6, d = idx & 63;
    float s = Ssum[0][q] + Ssum[1][q] + Ssum[2][q] + Ssum[3][q];
    float ov = Opart[0][q][d] + Opart[1][q][d] + Opart[2][q][d] + Opart[3][q][d];
    out[(size_t)(hh * NN + q0 + q) * DOUT + d] = ov / s;
  }
}

extern "C" void kernel_launch(void* const* d_in, const int* in_sizes, int n_in,
                              void* d_out, int out_size, void* d_ws, size_t ws_size,
                              hipStream_t stream) {
  const float* adj = (const float*)d_in[0];
  const float* h   = (const float*)d_in[1];
  const float* WQ  = (const float*)d_in[2];
  const float* bQ  = (const float*)d_in[3];
  const float* WK  = (const float*)d_in[4];
  const float* bK  = (const float*)d_in[5];
  const float* WV  = (const float*)d_in[6];
  const float* bV  = (const float*)d_in[7];
  float* out = (float*)d_out;

  if (ws_size < 12976128) return;  // need ~12.4 MB scratch

  char* ws = (char*)d_ws;
  bf16_t* hb = (bf16_t*)ws;                 // [N][256] bf16            3,145,728 B
  bf16_t* Wt = (bf16_t*)(ws + 3145728);     // [3][H][64][256] bf16       393,216 B
  bf16_t* Qb = (bf16_t*)(ws + 3538944);     // [H][N][64] bf16 (scaled) 3,145,728 B
  bf16_t* Kb = (bf16_t*)(ws + 6684672);     // [H][N][64] bf16          3,145,728 B
  bf16_t* Vt = (bf16_t*)(ws + 9830400);     // [H][64][N] bf16          3,145,728 B

  prep_kernel<<<1024, 256, 0, stream>>>(h, WQ, WK, WV, hb, Wt);
  proj_kernel<<<dim3(96, 4), 256, 0, stream>>>(hb, Wt, bQ, bK, bV, Qb, Kb, Vt);
  attn_kernel<<<dim3(192, 4), 256, 0, stream>>>(adj, Qb, Kb, Vt, out);
}